// Round 8
// baseline (585.796 us; speedup 1.0000x reference)
//
#include <hip/hip_runtime.h>
#include <hip/hip_bf16.h>

#define N_NODES 50000
#define N_EDGES 1600000
#define NFEAT   512
#define HIDDEN  128
#define NCLASS  40

#define SCAN_BLOCKS 196  // ceil(50000/256)
#define NREP 8           // atomic replicas (~XCD count)
#define ROWBLKS 12500    // spmm1 row-blocks per column quarter

typedef short short8 __attribute__((ext_vector_type(8)));
typedef float f32x4  __attribute__((ext_vector_type(4)));

// bf16 bits (RNE) from float
__device__ __forceinline__ unsigned short f2bu(float f) {
  __hip_bfloat16 h = __float2bfloat16(f);
  return *reinterpret_cast<unsigned short*>(&h);
}

// ---------------------------------------------------------------------------
// JAX threefry2x32, key (0,42), partitionable: bits[i] = o0^o1 of ctr (0,i).
// keep iff (bits>>31)==0.  (verified r2-r7)
// ---------------------------------------------------------------------------
__device__ __forceinline__ unsigned rotl32(unsigned x, int n) {
  return (x << n) | (x >> (32 - n));
}

__device__ __forceinline__ unsigned threefry_bits(unsigned x1) {
  unsigned x0 = 0u;
  const unsigned ks0 = 0u, ks1 = 42u, ks2 = 0x1BD11BDAu ^ 42u;
  x0 += ks0; x1 += ks1;
#define TFR(r) { x0 += x1; x1 = rotl32(x1, (r)); x1 ^= x0; }
  TFR(13) TFR(15) TFR(26) TFR(6)
  x0 += ks1; x1 += ks2 + 1u;
  TFR(17) TFR(29) TFR(16) TFR(24)
  x0 += ks2; x1 += ks0 + 2u;
  TFR(13) TFR(15) TFR(26) TFR(6)
  x0 += ks0; x1 += ks1 + 3u;
  TFR(17) TFR(29) TFR(16) TFR(24)
  x0 += ks1; x1 += ks2 + 4u;
  TFR(13) TFR(15) TFR(26) TFR(6)
  x0 += ks2; x1 += ks0 + 5u;
#undef TFR
  return x0 ^ x1;
}

// ---------------------------------------------------------------------------
// CSR build: replica histogram+pack -> hierarchical scan (also builds
// per-replica cursors) -> 2-pass scatter with replica cursors. (r6/r7)
// ---------------------------------------------------------------------------
__global__ __launch_bounds__(256) void hist_pack_kernel(
    const int* __restrict__ erow, const int* __restrict__ ecol,
    const float* __restrict__ evals, int* __restrict__ deg_r,
    unsigned* __restrict__ pval) {
  unsigned e = blockIdx.x * 256 + threadIdx.x;  // grid exact: 1.6M
  int r = erow[e];
  atomicAdd(&deg_r[(blockIdx.x & (NREP - 1)) * N_NODES + r], 1);
  pval[e] = (unsigned)ecol[e] | ((unsigned)f2bu(evals[e]) << 16);
}

__global__ __launch_bounds__(256) void partial_kernel(
    const int* __restrict__ deg_r, int* __restrict__ blocksum) {
  const int i = blockIdx.x * 256 + threadIdx.x;
  int v = 0;
  if (i < N_NODES) {
#pragma unroll
    for (int r = 0; r < NREP; r++) v += deg_r[r * N_NODES + i];
  }
#pragma unroll
  for (int off = 32; off >= 1; off >>= 1) v += __shfl_down(v, off);
  __shared__ int ws[4];
  if ((threadIdx.x & 63) == 0) ws[threadIdx.x >> 6] = v;
  __syncthreads();
  if (threadIdx.x == 0)
    blocksum[blockIdx.x] = ws[0] + ws[1] + ws[2] + ws[3];
}

__global__ __launch_bounds__(256) void scanblk_kernel(
    int* __restrict__ blocksum) {
  __shared__ int s[256];
  const int t = threadIdx.x;
  s[t] = (t < SCAN_BLOCKS) ? blocksum[t] : 0;
  __syncthreads();
#pragma unroll
  for (int off = 1; off < 256; off <<= 1) {
    int v = (t >= off) ? s[t - off] : 0;
    __syncthreads();
    s[t] += v;
    __syncthreads();
  }
  if (t < SCAN_BLOCKS) blocksum[t] = (t == 0) ? 0 : s[t - 1];  // exclusive
}

__global__ __launch_bounds__(256) void final_kernel(
    const int* __restrict__ deg_r, const int* __restrict__ blocksum,
    int* __restrict__ rowptr, int* __restrict__ coff) {
  __shared__ int s[256];
  const int t = threadIdx.x;
  const int i = blockIdx.x * 256 + t;
  int d[NREP];
  int tot = 0;
  if (i < N_NODES) {
#pragma unroll
    for (int r = 0; r < NREP; r++) {
      d[r] = deg_r[r * N_NODES + i];
      tot += d[r];
    }
  }
  s[t] = tot;
  __syncthreads();
#pragma unroll
  for (int off = 1; off < 256; off <<= 1) {
    int v = (t >= off) ? s[t - off] : 0;
    __syncthreads();
    s[t] += v;
    __syncthreads();
  }
  if (i < N_NODES) {
    int pre = blocksum[blockIdx.x] + s[t] - tot;  // exclusive prefix
    rowptr[i] = pre;
    int run = pre;
#pragma unroll
    for (int r = 0; r < NREP; r++) {
      coff[r * N_NODES + i] = run;
      run += d[r];
    }
    if (i == N_NODES - 1) rowptr[N_NODES] = N_EDGES;
  }
}

__global__ __launch_bounds__(256) void scatter_kernel(
    const int* __restrict__ erow, const unsigned* __restrict__ pval,
    int* __restrict__ coff, unsigned* __restrict__ csr, int rowLo, int rowHi) {
  unsigned e = blockIdx.x * 256 + threadIdx.x;
  int r = erow[e];
  if (r < rowLo || r >= rowHi) return;
  int p = atomicAdd(&coff[(blockIdx.x & (NREP - 1)) * N_NODES + r], 1);
  csr[p] = pval[e];
}

// ---------------------------------------------------------------------------
// W1T[n][k] = bf16(W1[k][n])  (128 x 512 bf16)
// ---------------------------------------------------------------------------
__global__ __launch_bounds__(256) void w1t_kernel(
    const float* __restrict__ W1, unsigned short* __restrict__ W1T) {
  int id = blockIdx.x * 256 + threadIdx.x;  // 65536 exact
  int n = id & 127, k = id >> 7;
  W1T[n * NFEAT + k] = f2bu(W1[k * HIDDEN + n]);
}

// ---------------------------------------------------------------------------
// GEMM1 (MFMA bf16): support = bf16(x) @ bf16(W1), fp32 acc. (r4-verified)
// ---------------------------------------------------------------------------
__global__ __launch_bounds__(256) void gemm1_mfma(
    const float* __restrict__ x, const unsigned short* __restrict__ W1T,
    unsigned short* __restrict__ support) {
  __shared__ short8 As[512];  // chunk = q*128 + row
  __shared__ short8 Bs[512];  // chunk = q*128 + col
  const int t = threadIdx.x;
  const int lane = t & 63;
  const int w = t >> 6;
  const int quad = lane >> 4;
  const int l15 = lane & 15;
  const int node_base = blockIdx.x * 128;
  const int mbase = (w >> 1) * 64;
  const int nbase = (w & 1) * 64;

  f32x4 acc[4][4] = {};

  for (int k0 = 0; k0 < NFEAT; k0 += 32) {
#pragma unroll
    for (int i = 0; i < 2; i++) {
      int lin = i * 256 + t;        // 0..511
      int n = lin >> 2, q = lin & 3;
      int row = node_base + n;
      if (row >= N_NODES) row = N_NODES - 1;
      const float* src = &x[(size_t)row * NFEAT + k0 + q * 8];
      float4 a = *(const float4*)src;
      float4 b = *(const float4*)(src + 4);
      short8 p;
      p[0] = (short)f2bu(a.x); p[1] = (short)f2bu(a.y);
      p[2] = (short)f2bu(a.z); p[3] = (short)f2bu(a.w);
      p[4] = (short)f2bu(b.x); p[5] = (short)f2bu(b.y);
      p[6] = (short)f2bu(b.z); p[7] = (short)f2bu(b.w);
      As[q * 128 + n] = p;
      Bs[q * 128 + n] = *(const short8*)&W1T[(size_t)n * NFEAT + k0 + q * 8];
    }
    __syncthreads();
    short8 af[4], bfr[4];
#pragma unroll
    for (int mt = 0; mt < 4; mt++)
      af[mt] = As[quad * 128 + mbase + mt * 16 + l15];
#pragma unroll
    for (int nt = 0; nt < 4; nt++)
      bfr[nt] = Bs[quad * 128 + nbase + nt * 16 + l15];
#pragma unroll
    for (int mt = 0; mt < 4; mt++)
#pragma unroll
      for (int nt = 0; nt < 4; nt++)
        acc[mt][nt] = __builtin_amdgcn_mfma_f32_16x16x32_bf16(
            af[mt], bfr[nt], acc[mt][nt], 0, 0, 0);
    __syncthreads();
  }

#pragma unroll
  for (int mt = 0; mt < 4; mt++)
#pragma unroll
    for (int nt = 0; nt < 4; nt++)
#pragma unroll
      for (int r = 0; r < 4; r++) {
        int row = node_base + mbase + mt * 16 + quad * 4 + r;
        int col = nbase + nt * 16 + l15;
        if (row < N_NODES)
          support[(size_t)row * HIDDEN + col] = f2bu(acc[mt][nt][r]);
      }
}

// ---------------------------------------------------------------------------
// SpMM1 fused, column-quartered + edge-packed:
// quarter q = blockIdx.x / 12500 covers support cols [q*32, q*32+32)
// (3.2 MB slice -> L2-resident within the quarter's dispatch window).
// Wave handles 1 row; 4 edges per iter (16 lanes each, one 64B line/edge),
// 2x unrolled; shfl_xor(16,32) reduces edge-subgroups.
// h[row, quarter cols] = bf16(dropout(relu(sum + b1)))
// ---------------------------------------------------------------------------
__global__ __launch_bounds__(256) void spmm1_fused(
    const unsigned* __restrict__ csr, const int* __restrict__ rowptr,
    const unsigned* __restrict__ sup,  // support rows = 64 uints (bf162)
    const float* __restrict__ b1, unsigned* __restrict__ h) {
  const int bx = blockIdx.x;
  const int q = bx / ROWBLKS;          // column quarter 0..3
  const int rb = bx - q * ROWBLKS;
  const int row = rb * 4 + (threadIdx.x >> 6);
  const int lane = threadIdx.x & 63;
  const int g = lane >> 4;             // edge subgroup 0..3
  const int l15 = lane & 15;
  const int beg = rowptr[row], end = rowptr[row + 1];
  const unsigned qoff = q * 16 + l15;
  float ax = 0.f, ay = 0.f;
  for (int j = beg; j < end; j += 8) {
    int je0 = j + g;
    int je1 = j + 4 + g;
    int jc0 = (je0 < end) ? je0 : (end - 1);
    int jc1 = (je1 < end) ? je1 : (end - 1);
    unsigned p0 = __builtin_nontemporal_load(&csr[jc0]);
    unsigned p1 = __builtin_nontemporal_load(&csr[jc1]);
    unsigned u0 = sup[(p0 & 0xffffu) * 64 + qoff];
    unsigned u1 = sup[(p1 & 0xffffu) * 64 + qoff];
    float v0 = (je0 < end) ? __uint_as_float(p0 & 0xffff0000u) : 0.f;
    float v1 = (je1 < end) ? __uint_as_float(p1 & 0xffff0000u) : 0.f;
    ax += v0 * __uint_as_float(u0 << 16) + v1 * __uint_as_float(u1 << 16);
    ay += v0 * __uint_as_float(u0 & 0xffff0000u) +
          v1 * __uint_as_float(u1 & 0xffff0000u);
  }
  ax += __shfl_xor(ax, 16); ay += __shfl_xor(ay, 16);
  ax += __shfl_xor(ax, 32); ay += __shfl_xor(ay, 32);
  if (g == 0) {
    const unsigned colbase = q * 32 + l15 * 2;
    const unsigned i0 = (unsigned)row * HIDDEN + colbase;
    float vx = fmaxf(ax + b1[colbase], 0.f);
    float vy = fmaxf(ay + b1[colbase + 1], 0.f);
    vx = (threefry_bits(i0) >> 31) ? 0.f : 2.f * vx;
    vy = (threefry_bits(i0 + 1) >> 31) ? 0.f : 2.f * vy;
    h[(unsigned)row * 64 + q * 16 + l15] =
        (unsigned)f2bu(vx) | ((unsigned)f2bu(vy) << 16);
  }
}

// ---------------------------------------------------------------------------
// GEMM2: h2[50000,40] = h(bf16) @ W2, fp32 compute, bf16 out. (r4-verified)
// ---------------------------------------------------------------------------
__global__ __launch_bounds__(256) void gemm2_kernel(
    const uint4* __restrict__ h,  // rows = 16 uint4 (8 bf16 each)
    const float* __restrict__ W2, unsigned short* __restrict__ h2) {
  __shared__ float Hs[64][132];
  __shared__ float Ws[40][132];
  const int t = threadIdx.x;
  const int node_base = blockIdx.x * 64;
#pragma unroll
  for (int i = 0; i < 4; i++) {
    int lin = i * 256 + t;
    int nloc = lin >> 4, c8 = lin & 15;
    int n = node_base + nloc;
    if (n >= N_NODES) n = N_NODES - 1;
    uint4 u = h[(size_t)n * 16 + c8];
    float* d = &Hs[nloc][c8 * 8];
    d[0] = __uint_as_float(u.x << 16); d[1] = __uint_as_float(u.x & 0xffff0000u);
    d[2] = __uint_as_float(u.y << 16); d[3] = __uint_as_float(u.y & 0xffff0000u);
    d[4] = __uint_as_float(u.z << 16); d[5] = __uint_as_float(u.z & 0xffff0000u);
    d[6] = __uint_as_float(u.w << 16); d[7] = __uint_as_float(u.w & 0xffff0000u);
  }
#pragma unroll
  for (int i = 0; i < 20; i++) {
    int l = t + i * 256;
    int k = l / NCLASS, f = l % NCLASS;
    Ws[f][k] = W2[l];
  }
  __syncthreads();
  const int nloc = t >> 2;
  const int fb = t & 3;
  const int n = node_base + nloc;
  float acc[10];
#pragma unroll
  for (int j = 0; j < 10; j++) acc[j] = 0.f;
  for (int k = 0; k < HIDDEN; k += 4) {
    float4 a = *(const float4*)&Hs[nloc][k];
#pragma unroll
    for (int j = 0; j < 10; j++) {
      float4 wv = *(const float4*)&Ws[fb + 4 * j][k];
      acc[j] += a.x * wv.x + a.y * wv.y + a.z * wv.z + a.w * wv.w;
    }
  }
  if (n < N_NODES) {
#pragma unroll
    for (int j = 0; j < 10; j++)
      h2[(size_t)n * NCLASS + fb + 4 * j] = f2bu(acc[j]);
  }
}

// ---------------------------------------------------------------------------
// SpMM2 fused: wave per row, 4 edges in flight (half-split x 2-unroll).
// ---------------------------------------------------------------------------
__global__ __launch_bounds__(256) void spmm2_fused(
    const unsigned* __restrict__ csr, const int* __restrict__ rowptr,
    const unsigned* __restrict__ h2u,  // rows = 20 uints
    const float* __restrict__ b2, float* __restrict__ out) {
  const int row = blockIdx.x * 4 + (threadIdx.x >> 6);
  const int lane = threadIdx.x & 63;
  const int half = lane >> 5;
  const int il = lane & 31;
  const unsigned ilc = (il < 20) ? (unsigned)il : 19u;
  const int beg = rowptr[row], end = rowptr[row + 1];
  float ax = 0.f, ay = 0.f;
  int j = beg + half;
  for (; j + 2 < end; j += 4) {
    unsigned p0 = __builtin_nontemporal_load(&csr[j]);
    unsigned p1 = __builtin_nontemporal_load(&csr[j + 2]);
    unsigned u0 = h2u[(p0 & 0xffffu) * 20 + ilc];
    unsigned u1 = h2u[(p1 & 0xffffu) * 20 + ilc];
    float v0 = __uint_as_float(p0 & 0xffff0000u);
    float v1 = __uint_as_float(p1 & 0xffff0000u);
    ax += v0 * __uint_as_float(u0 << 16) + v1 * __uint_as_float(u1 << 16);
    ay += v0 * __uint_as_float(u0 & 0xffff0000u) +
          v1 * __uint_as_float(u1 & 0xffff0000u);
  }
  for (; j < end; j += 2) {
    unsigned p0 = __builtin_nontemporal_load(&csr[j]);
    unsigned u0 = h2u[(p0 & 0xffffu) * 20 + ilc];
    float v0 = __uint_as_float(p0 & 0xffff0000u);
    ax += v0 * __uint_as_float(u0 << 16);
    ay += v0 * __uint_as_float(u0 & 0xffff0000u);
  }
  ax += __shfl_xor(ax, 32);
  ay += __shfl_xor(ay, 32);
  if (half == 0 && il < 20) {
    float2 r;
    r.x = fmaxf(ax + b2[il * 2], 0.f);
    r.y = fmaxf(ay + b2[il * 2 + 1], 0.f);
    *(float2*)&out[(unsigned)row * NCLASS + il * 2] = r;
  }
}

extern "C" void kernel_launch(void* const* d_in, const int* in_sizes, int n_in,
                              void* d_out, int out_size, void* d_ws,
                              size_t ws_size, hipStream_t stream) {
  const float* x     = (const float*)d_in[0];
  const int*   erow  = (const int*)d_in[1];
  const int*   ecol  = (const int*)d_in[2];
  const float* evals = (const float*)d_in[3];
  const float* W1    = (const float*)d_in[4];
  const float* b1    = (const float*)d_in[5];
  const float* W2    = (const float*)d_in[6];
  const float* b2    = (const float*)d_in[7];
  float* out = (float*)d_out;

  // ws layout (bytes): support 12.8M | h 12.8M | h2 4M | W1T 128K |
  // csr 6.4M | pval 6.4M | rowptr 200K | blocksum 1K | deg_r 1.6M |
  // coff 1.6M   (~46 MB)
  char* base = (char*)d_ws;
  unsigned short* support = (unsigned short*)base;
  unsigned short* h   = (unsigned short*)(base + 12800000);
  unsigned short* h2  = (unsigned short*)(base + 25600000);
  unsigned short* W1T = (unsigned short*)(base + 29600000);
  unsigned* csr  = (unsigned*)(base + 29731072);
  unsigned* pval = (unsigned*)(base + 29731072 + (size_t)N_EDGES * 4);
  int* rowptr   = (int*)(base + 29731072 + (size_t)N_EDGES * 8);
  int* blocksum = rowptr + (N_NODES + 1);
  int* deg_r    = blocksum + 256;
  int* coff     = deg_r + NREP * N_NODES;

  hipMemsetAsync(deg_r, 0, NREP * N_NODES * sizeof(int), stream);

  hist_pack_kernel<<<N_EDGES / 256, 256, 0, stream>>>(erow, ecol, evals,
                                                      deg_r, pval);
  partial_kernel<<<SCAN_BLOCKS, 256, 0, stream>>>(deg_r, blocksum);
  scanblk_kernel<<<1, 256, 0, stream>>>(blocksum);
  final_kernel<<<SCAN_BLOCKS, 256, 0, stream>>>(deg_r, blocksum, rowptr, coff);
  // 2 row-range passes: each pass's csr write region (~3.2 MB) fits per-XCD L2
  scatter_kernel<<<N_EDGES / 256, 256, 0, stream>>>(erow, pval, coff, csr,
                                                    0, 25000);
  scatter_kernel<<<N_EDGES / 256, 256, 0, stream>>>(erow, pval, coff, csr,
                                                    25000, 50000);

  w1t_kernel<<<256, 256, 0, stream>>>(W1, W1T);
  gemm1_mfma<<<(N_NODES + 127) / 128, 256, 0, stream>>>(x, W1T, support);
  spmm1_fused<<<4 * ROWBLKS, 256, 0, stream>>>(csr, rowptr,
                                               (const unsigned*)support, b1,
                                               (unsigned*)h);
  gemm2_kernel<<<(N_NODES + 63) / 64, 256, 0, stream>>>((const uint4*)h, W2, h2);
  spmm2_fused<<<N_NODES / 4, 256, 0, stream>>>(csr, rowptr,
                                               (const unsigned*)h2, b2, out);
}

// Round 9
// 542.448 us; speedup vs baseline: 1.0799x; 1.0799x over previous
//
#include <hip/hip_runtime.h>
#include <hip/hip_bf16.h>

#define N_NODES 50000
#define N_EDGES 1600000
#define NFEAT   512
#define HIDDEN  128
#define NCLASS  40

#define SCAN_BLOCKS 196  // ceil(50000/256)
#define NREP 8           // atomic replicas (~XCD count)
#define ROWBLKS 12500    // spmm1 row-blocks per column quarter
#define QSTRIDE (N_NODES * 16)  // uints per support quarter (50000 rows x 64B)

typedef short short8 __attribute__((ext_vector_type(8)));
typedef float f32x4  __attribute__((ext_vector_type(4)));

// bf16 bits (RNE) from float
__device__ __forceinline__ unsigned short f2bu(float f) {
  __hip_bfloat16 h = __float2bfloat16(f);
  return *reinterpret_cast<unsigned short*>(&h);
}

// ---------------------------------------------------------------------------
// JAX threefry2x32, key (0,42), partitionable: bits[i] = o0^o1 of ctr (0,i).
// keep iff (bits>>31)==0.  (verified r2-r8)
// ---------------------------------------------------------------------------
__device__ __forceinline__ unsigned rotl32(unsigned x, int n) {
  return (x << n) | (x >> (32 - n));
}

__device__ __forceinline__ unsigned threefry_bits(unsigned x1) {
  unsigned x0 = 0u;
  const unsigned ks0 = 0u, ks1 = 42u, ks2 = 0x1BD11BDAu ^ 42u;
  x0 += ks0; x1 += ks1;
#define TFR(r) { x0 += x1; x1 = rotl32(x1, (r)); x1 ^= x0; }
  TFR(13) TFR(15) TFR(26) TFR(6)
  x0 += ks1; x1 += ks2 + 1u;
  TFR(17) TFR(29) TFR(16) TFR(24)
  x0 += ks2; x1 += ks0 + 2u;
  TFR(13) TFR(15) TFR(26) TFR(6)
  x0 += ks0; x1 += ks1 + 3u;
  TFR(17) TFR(29) TFR(16) TFR(24)
  x0 += ks1; x1 += ks2 + 4u;
  TFR(13) TFR(15) TFR(26) TFR(6)
  x0 += ks2; x1 += ks0 + 5u;
#undef TFR
  return x0 ^ x1;
}

// ---------------------------------------------------------------------------
// CSR build: replica histogram+pack -> hierarchical scan (also builds
// per-replica cursors) -> 2-pass scatter with replica cursors. (r6/r7)
// ---------------------------------------------------------------------------
__global__ __launch_bounds__(256) void hist_pack_kernel(
    const int* __restrict__ erow, const int* __restrict__ ecol,
    const float* __restrict__ evals, int* __restrict__ deg_r,
    unsigned* __restrict__ pval) {
  unsigned e = blockIdx.x * 256 + threadIdx.x;  // grid exact: 1.6M
  int r = erow[e];
  atomicAdd(&deg_r[(blockIdx.x & (NREP - 1)) * N_NODES + r], 1);
  pval[e] = (unsigned)ecol[e] | ((unsigned)f2bu(evals[e]) << 16);
}

__global__ __launch_bounds__(256) void partial_kernel(
    const int* __restrict__ deg_r, int* __restrict__ blocksum) {
  const int i = blockIdx.x * 256 + threadIdx.x;
  int v = 0;
  if (i < N_NODES) {
#pragma unroll
    for (int r = 0; r < NREP; r++) v += deg_r[r * N_NODES + i];
  }
#pragma unroll
  for (int off = 32; off >= 1; off >>= 1) v += __shfl_down(v, off);
  __shared__ int ws[4];
  if ((threadIdx.x & 63) == 0) ws[threadIdx.x >> 6] = v;
  __syncthreads();
  if (threadIdx.x == 0)
    blocksum[blockIdx.x] = ws[0] + ws[1] + ws[2] + ws[3];
}

__global__ __launch_bounds__(256) void scanblk_kernel(
    int* __restrict__ blocksum) {
  __shared__ int s[256];
  const int t = threadIdx.x;
  s[t] = (t < SCAN_BLOCKS) ? blocksum[t] : 0;
  __syncthreads();
#pragma unroll
  for (int off = 1; off < 256; off <<= 1) {
    int v = (t >= off) ? s[t - off] : 0;
    __syncthreads();
    s[t] += v;
    __syncthreads();
  }
  if (t < SCAN_BLOCKS) blocksum[t] = (t == 0) ? 0 : s[t - 1];  // exclusive
}

__global__ __launch_bounds__(256) void final_kernel(
    const int* __restrict__ deg_r, const int* __restrict__ blocksum,
    int* __restrict__ rowptr, int* __restrict__ coff) {
  __shared__ int s[256];
  const int t = threadIdx.x;
  const int i = blockIdx.x * 256 + t;
  int d[NREP];
  int tot = 0;
  if (i < N_NODES) {
#pragma unroll
    for (int r = 0; r < NREP; r++) {
      d[r] = deg_r[r * N_NODES + i];
      tot += d[r];
    }
  }
  s[t] = tot;
  __syncthreads();
#pragma unroll
  for (int off = 1; off < 256; off <<= 1) {
    int v = (t >= off) ? s[t - off] : 0;
    __syncthreads();
    s[t] += v;
    __syncthreads();
  }
  if (i < N_NODES) {
    int pre = blocksum[blockIdx.x] + s[t] - tot;  // exclusive prefix
    rowptr[i] = pre;
    int run = pre;
#pragma unroll
    for (int r = 0; r < NREP; r++) {
      coff[r * N_NODES + i] = run;
      run += d[r];
    }
    if (i == N_NODES - 1) rowptr[N_NODES] = N_EDGES;
  }
}

__global__ __launch_bounds__(256) void scatter_kernel(
    const int* __restrict__ erow, const unsigned* __restrict__ pval,
    int* __restrict__ coff, unsigned* __restrict__ csr, int rowLo, int rowHi) {
  unsigned e = blockIdx.x * 256 + threadIdx.x;
  int r = erow[e];
  if (r < rowLo || r >= rowHi) return;
  int p = atomicAdd(&coff[(blockIdx.x & (NREP - 1)) * N_NODES + r], 1);
  csr[p] = pval[e];
}

// ---------------------------------------------------------------------------
// W1T[n][k] = bf16(W1[k][n])  (128 x 512 bf16)
// ---------------------------------------------------------------------------
__global__ __launch_bounds__(256) void w1t_kernel(
    const float* __restrict__ W1, unsigned short* __restrict__ W1T) {
  int id = blockIdx.x * 256 + threadIdx.x;  // 65536 exact
  int n = id & 127, k = id >> 7;
  W1T[n * NFEAT + k] = f2bu(W1[k * HIDDEN + n]);
}

// ---------------------------------------------------------------------------
// GEMM1 (MFMA bf16): support = bf16(x) @ bf16(W1), fp32 acc.
// Epilogue writes QUARTER-MAJOR support: sup4[col/32][row][col%32] so each
// spmm1 quarter slice is a CONTIGUOUS 3.2 MB region (full L2 set coverage;
// r8's strided slice aliased into 1/4 of the sets and thrashed).
// ---------------------------------------------------------------------------
__global__ __launch_bounds__(256) void gemm1_mfma(
    const float* __restrict__ x, const unsigned short* __restrict__ W1T,
    unsigned short* __restrict__ support) {
  __shared__ short8 As[512];  // chunk = q*128 + row
  __shared__ short8 Bs[512];  // chunk = q*128 + col
  const int t = threadIdx.x;
  const int lane = t & 63;
  const int w = t >> 6;
  const int quad = lane >> 4;
  const int l15 = lane & 15;
  const int node_base = blockIdx.x * 128;
  const int mbase = (w >> 1) * 64;
  const int nbase = (w & 1) * 64;

  f32x4 acc[4][4] = {};

  for (int k0 = 0; k0 < NFEAT; k0 += 32) {
#pragma unroll
    for (int i = 0; i < 2; i++) {
      int lin = i * 256 + t;        // 0..511
      int n = lin >> 2, q = lin & 3;
      int row = node_base + n;
      if (row >= N_NODES) row = N_NODES - 1;
      const float* src = &x[(size_t)row * NFEAT + k0 + q * 8];
      float4 a = *(const float4*)src;
      float4 b = *(const float4*)(src + 4);
      short8 p;
      p[0] = (short)f2bu(a.x); p[1] = (short)f2bu(a.y);
      p[2] = (short)f2bu(a.z); p[3] = (short)f2bu(a.w);
      p[4] = (short)f2bu(b.x); p[5] = (short)f2bu(b.y);
      p[6] = (short)f2bu(b.z); p[7] = (short)f2bu(b.w);
      As[q * 128 + n] = p;
      Bs[q * 128 + n] = *(const short8*)&W1T[(size_t)n * NFEAT + k0 + q * 8];
    }
    __syncthreads();
    short8 af[4], bfr[4];
#pragma unroll
    for (int mt = 0; mt < 4; mt++)
      af[mt] = As[quad * 128 + mbase + mt * 16 + l15];
#pragma unroll
    for (int nt = 0; nt < 4; nt++)
      bfr[nt] = Bs[quad * 128 + nbase + nt * 16 + l15];
#pragma unroll
    for (int mt = 0; mt < 4; mt++)
#pragma unroll
      for (int nt = 0; nt < 4; nt++)
        acc[mt][nt] = __builtin_amdgcn_mfma_f32_16x16x32_bf16(
            af[mt], bfr[nt], acc[mt][nt], 0, 0, 0);
    __syncthreads();
  }

#pragma unroll
  for (int mt = 0; mt < 4; mt++)
#pragma unroll
    for (int nt = 0; nt < 4; nt++)
#pragma unroll
      for (int r = 0; r < 4; r++) {
        int row = node_base + mbase + mt * 16 + quad * 4 + r;
        int col = nbase + nt * 16 + l15;
        if (row < N_NODES)
          support[(size_t)(col >> 5) * (N_NODES * 32) + (size_t)row * 32 +
                  (col & 31)] = f2bu(acc[mt][nt][r]);
      }
}

// ---------------------------------------------------------------------------
// SpMM1 fused, column-quartered over CONTIGUOUS quarter-major support.
// quarter q = blockIdx.x / ROWBLKS covers sup4 quarter q (contiguous 3.2 MB
// -> L2-resident in the quarter's dispatch window). Wave = 1 row; 8 edges
// per iter (16 lanes/edge, one 64B line), 2 in flight; shfl_xor reduce.
// h[row, q cols] = bf16(dropout(relu(sum + b1)))
// ---------------------------------------------------------------------------
__global__ __launch_bounds__(256) void spmm1_fused(
    const unsigned* __restrict__ csr, const int* __restrict__ rowptr,
    const unsigned* __restrict__ sup,  // quarter-major: q*QSTRIDE + c*16 + l
    const float* __restrict__ b1, unsigned* __restrict__ h) {
  const int bx = blockIdx.x;
  const int q = bx / ROWBLKS;          // column quarter 0..3
  const int rb = bx - q * ROWBLKS;
  const int row = rb * 4 + (threadIdx.x >> 6);
  const int lane = threadIdx.x & 63;
  const int g = lane >> 4;             // edge subgroup 0..3
  const int l15 = lane & 15;
  const int beg = rowptr[row], end = rowptr[row + 1];
  const unsigned qbase = (unsigned)q * QSTRIDE + l15;
  float ax = 0.f, ay = 0.f;
  for (int j = beg; j < end; j += 8) {
    int je0 = j + g;
    int je1 = j + 4 + g;
    int jc0 = (je0 < end) ? je0 : (end - 1);
    int jc1 = (je1 < end) ? je1 : (end - 1);
    unsigned p0 = csr[jc0];
    unsigned p1 = csr[jc1];
    unsigned u0 = sup[qbase + (p0 & 0xffffu) * 16];
    unsigned u1 = sup[qbase + (p1 & 0xffffu) * 16];
    float v0 = (je0 < end) ? __uint_as_float(p0 & 0xffff0000u) : 0.f;
    float v1 = (je1 < end) ? __uint_as_float(p1 & 0xffff0000u) : 0.f;
    ax += v0 * __uint_as_float(u0 << 16) + v1 * __uint_as_float(u1 << 16);
    ay += v0 * __uint_as_float(u0 & 0xffff0000u) +
          v1 * __uint_as_float(u1 & 0xffff0000u);
  }
  ax += __shfl_xor(ax, 16); ay += __shfl_xor(ay, 16);
  ax += __shfl_xor(ax, 32); ay += __shfl_xor(ay, 32);
  if (g == 0) {
    const unsigned colbase = q * 32 + l15 * 2;
    const unsigned i0 = (unsigned)row * HIDDEN + colbase;
    float vx = fmaxf(ax + b1[colbase], 0.f);
    float vy = fmaxf(ay + b1[colbase + 1], 0.f);
    vx = (threefry_bits(i0) >> 31) ? 0.f : 2.f * vx;
    vy = (threefry_bits(i0 + 1) >> 31) ? 0.f : 2.f * vy;
    h[(unsigned)row * 64 + q * 16 + l15] =
        (unsigned)f2bu(vx) | ((unsigned)f2bu(vy) << 16);
  }
}

// ---------------------------------------------------------------------------
// GEMM2: h2[50000,40] = h(bf16) @ W2, fp32 compute, bf16 out. (r4-verified)
// ---------------------------------------------------------------------------
__global__ __launch_bounds__(256) void gemm2_kernel(
    const uint4* __restrict__ h,  // rows = 16 uint4 (8 bf16 each)
    const float* __restrict__ W2, unsigned short* __restrict__ h2) {
  __shared__ float Hs[64][132];
  __shared__ float Ws[40][132];
  const int t = threadIdx.x;
  const int node_base = blockIdx.x * 64;
#pragma unroll
  for (int i = 0; i < 4; i++) {
    int lin = i * 256 + t;
    int nloc = lin >> 4, c8 = lin & 15;
    int n = node_base + nloc;
    if (n >= N_NODES) n = N_NODES - 1;
    uint4 u = h[(size_t)n * 16 + c8];
    float* d = &Hs[nloc][c8 * 8];
    d[0] = __uint_as_float(u.x << 16); d[1] = __uint_as_float(u.x & 0xffff0000u);
    d[2] = __uint_as_float(u.y << 16); d[3] = __uint_as_float(u.y & 0xffff0000u);
    d[4] = __uint_as_float(u.z << 16); d[5] = __uint_as_float(u.z & 0xffff0000u);
    d[6] = __uint_as_float(u.w << 16); d[7] = __uint_as_float(u.w & 0xffff0000u);
  }
#pragma unroll
  for (int i = 0; i < 20; i++) {
    int l = t + i * 256;
    int k = l / NCLASS, f = l % NCLASS;
    Ws[f][k] = W2[l];
  }
  __syncthreads();
  const int nloc = t >> 2;
  const int fb = t & 3;
  const int n = node_base + nloc;
  float acc[10];
#pragma unroll
  for (int j = 0; j < 10; j++) acc[j] = 0.f;
  for (int k = 0; k < HIDDEN; k += 4) {
    float4 a = *(const float4*)&Hs[nloc][k];
#pragma unroll
    for (int j = 0; j < 10; j++) {
      float4 wv = *(const float4*)&Ws[fb + 4 * j][k];
      acc[j] += a.x * wv.x + a.y * wv.y + a.z * wv.z + a.w * wv.w;
    }
  }
  if (n < N_NODES) {
#pragma unroll
    for (int j = 0; j < 10; j++)
      h2[(size_t)n * NCLASS + fb + 4 * j] = f2bu(acc[j]);
  }
}

// ---------------------------------------------------------------------------
// SpMM2 fused: wave per row, 4 edges in flight (half-split x 2-unroll). (r7)
// ---------------------------------------------------------------------------
__global__ __launch_bounds__(256) void spmm2_fused(
    const unsigned* __restrict__ csr, const int* __restrict__ rowptr,
    const unsigned* __restrict__ h2u,  // rows = 20 uints
    const float* __restrict__ b2, float* __restrict__ out) {
  const int row = blockIdx.x * 4 + (threadIdx.x >> 6);
  const int lane = threadIdx.x & 63;
  const int half = lane >> 5;
  const int il = lane & 31;
  const unsigned ilc = (il < 20) ? (unsigned)il : 19u;
  const int beg = rowptr[row], end = rowptr[row + 1];
  float ax = 0.f, ay = 0.f;
  int j = beg + half;
  for (; j + 2 < end; j += 4) {
    unsigned p0 = csr[j];
    unsigned p1 = csr[j + 2];
    unsigned u0 = h2u[(p0 & 0xffffu) * 20 + ilc];
    unsigned u1 = h2u[(p1 & 0xffffu) * 20 + ilc];
    float v0 = __uint_as_float(p0 & 0xffff0000u);
    float v1 = __uint_as_float(p1 & 0xffff0000u);
    ax += v0 * __uint_as_float(u0 << 16) + v1 * __uint_as_float(u1 << 16);
    ay += v0 * __uint_as_float(u0 & 0xffff0000u) +
          v1 * __uint_as_float(u1 & 0xffff0000u);
  }
  for (; j < end; j += 2) {
    unsigned p0 = csr[j];
    unsigned u0 = h2u[(p0 & 0xffffu) * 20 + ilc];
    float v0 = __uint_as_float(p0 & 0xffff0000u);
    ax += v0 * __uint_as_float(u0 << 16);
    ay += v0 * __uint_as_float(u0 & 0xffff0000u);
  }
  ax += __shfl_xor(ax, 32);
  ay += __shfl_xor(ay, 32);
  if (half == 0 && il < 20) {
    float2 r;
    r.x = fmaxf(ax + b2[il * 2], 0.f);
    r.y = fmaxf(ay + b2[il * 2 + 1], 0.f);
    *(float2*)&out[(unsigned)row * NCLASS + il * 2] = r;
  }
}

extern "C" void kernel_launch(void* const* d_in, const int* in_sizes, int n_in,
                              void* d_out, int out_size, void* d_ws,
                              size_t ws_size, hipStream_t stream) {
  const float* x     = (const float*)d_in[0];
  const int*   erow  = (const int*)d_in[1];
  const int*   ecol  = (const int*)d_in[2];
  const float* evals = (const float*)d_in[3];
  const float* W1    = (const float*)d_in[4];
  const float* b1    = (const float*)d_in[5];
  const float* W2    = (const float*)d_in[6];
  const float* b2    = (const float*)d_in[7];
  float* out = (float*)d_out;

  // ws layout (bytes): support 12.8M | h 12.8M | h2 4M | W1T 128K |
  // csr 6.4M | pval 6.4M | rowptr 200K | blocksum 1K | deg_r 1.6M |
  // coff 1.6M   (~46 MB)
  char* base = (char*)d_ws;
  unsigned short* support = (unsigned short*)base;
  unsigned short* h   = (unsigned short*)(base + 12800000);
  unsigned short* h2  = (unsigned short*)(base + 25600000);
  unsigned short* W1T = (unsigned short*)(base + 29600000);
  unsigned* csr  = (unsigned*)(base + 29731072);
  unsigned* pval = (unsigned*)(base + 29731072 + (size_t)N_EDGES * 4);
  int* rowptr   = (int*)(base + 29731072 + (size_t)N_EDGES * 8);
  int* blocksum = rowptr + (N_NODES + 1);
  int* deg_r    = blocksum + 256;
  int* coff     = deg_r + NREP * N_NODES;

  hipMemsetAsync(deg_r, 0, NREP * N_NODES * sizeof(int), stream);

  hist_pack_kernel<<<N_EDGES / 256, 256, 0, stream>>>(erow, ecol, evals,
                                                      deg_r, pval);
  partial_kernel<<<SCAN_BLOCKS, 256, 0, stream>>>(deg_r, blocksum);
  scanblk_kernel<<<1, 256, 0, stream>>>(blocksum);
  final_kernel<<<SCAN_BLOCKS, 256, 0, stream>>>(deg_r, blocksum, rowptr, coff);
  // 2 row-range passes: each pass's csr write region (~3.2 MB) fits per-XCD L2
  scatter_kernel<<<N_EDGES / 256, 256, 0, stream>>>(erow, pval, coff, csr,
                                                    0, 25000);
  scatter_kernel<<<N_EDGES / 256, 256, 0, stream>>>(erow, pval, coff, csr,
                                                    25000, 50000);

  w1t_kernel<<<256, 256, 0, stream>>>(W1, W1T);
  gemm1_mfma<<<(N_NODES + 127) / 128, 256, 0, stream>>>(x, W1T, support);
  spmm1_fused<<<4 * ROWBLKS, 256, 0, stream>>>(csr, rowptr,
                                               (const unsigned*)support, b1,
                                               (unsigned*)h);
  gemm2_kernel<<<(N_NODES + 63) / 64, 256, 0, stream>>>((const uint4*)h, W2, h2);
  spmm2_fused<<<N_NODES / 4, 256, 0, stream>>>(csr, rowptr,
                                               (const unsigned*)h2, b2, out);
}

// Round 10
// 467.987 us; speedup vs baseline: 1.2517x; 1.1591x over previous
//
#include <hip/hip_runtime.h>
#include <hip/hip_bf16.h>

#define N_NODES 50000
#define N_EDGES 1600000
#define NFEAT   512
#define HIDDEN  128
#define NCLASS  40

#define SCAN_BLOCKS 196   // ceil(50000/256)
#define NREP 8            // atomic replicas (~XCD count)
#define HIST_BLOCKS (N_EDGES / 256)   // 6250
#define W1T_BLOCKS 256
#define GEMM1_BLOCKS ((N_NODES + 127) / 128)  // 391

typedef short short8 __attribute__((ext_vector_type(8)));
typedef float f32x4  __attribute__((ext_vector_type(4)));

// bf16 bits (RNE) from float
__device__ __forceinline__ unsigned short f2bu(float f) {
  __hip_bfloat16 h = __float2bfloat16(f);
  return *reinterpret_cast<unsigned short*>(&h);
}

// ---------------------------------------------------------------------------
// JAX threefry2x32, key (0,42), partitionable: bits[i] = o0^o1 of ctr (0,i).
// keep iff (bits>>31)==0.  (verified r2-r9)
// ---------------------------------------------------------------------------
__device__ __forceinline__ unsigned rotl32(unsigned x, int n) {
  return (x << n) | (x >> (32 - n));
}

__device__ __forceinline__ unsigned threefry_bits(unsigned x1) {
  unsigned x0 = 0u;
  const unsigned ks0 = 0u, ks1 = 42u, ks2 = 0x1BD11BDAu ^ 42u;
  x0 += ks0; x1 += ks1;
#define TFR(r) { x0 += x1; x1 = rotl32(x1, (r)); x1 ^= x0; }
  TFR(13) TFR(15) TFR(26) TFR(6)
  x0 += ks1; x1 += ks2 + 1u;
  TFR(17) TFR(29) TFR(16) TFR(24)
  x0 += ks2; x1 += ks0 + 2u;
  TFR(13) TFR(15) TFR(26) TFR(6)
  x0 += ks0; x1 += ks1 + 3u;
  TFR(17) TFR(29) TFR(16) TFR(24)
  x0 += ks1; x1 += ks2 + 4u;
  TFR(13) TFR(15) TFR(26) TFR(6)
  x0 += ks2; x1 += ks0 + 5u;
#undef TFR
  return x0 ^ x1;
}

// ---------------------------------------------------------------------------
// Fused: histogram+pack (blocks 0..6249) | W1 transpose (blocks 6250..6505).
// Independent work merged to overlap and save a launch.
// ---------------------------------------------------------------------------
__global__ __launch_bounds__(256) void hist_w1t_kernel(
    const int* __restrict__ erow, const int* __restrict__ ecol,
    const float* __restrict__ evals, int* __restrict__ deg_r,
    unsigned* __restrict__ pval, const float* __restrict__ W1,
    unsigned short* __restrict__ W1T) {
  if (blockIdx.x < HIST_BLOCKS) {
    unsigned e = blockIdx.x * 256 + threadIdx.x;
    int r = erow[e];
    atomicAdd(&deg_r[(blockIdx.x & (NREP - 1)) * N_NODES + r], 1);
    pval[e] = (unsigned)ecol[e] | ((unsigned)f2bu(evals[e]) << 16);
  } else {
    int id = (blockIdx.x - HIST_BLOCKS) * 256 + threadIdx.x;  // 65536 exact
    int n = id & 127, k = id >> 7;
    W1T[n * NFEAT + k] = f2bu(W1[k * HIDDEN + n]);
  }
}

__global__ __launch_bounds__(256) void partial_kernel(
    const int* __restrict__ deg_r, int* __restrict__ blocksum) {
  const int i = blockIdx.x * 256 + threadIdx.x;
  int v = 0;
  if (i < N_NODES) {
#pragma unroll
    for (int r = 0; r < NREP; r++) v += deg_r[r * N_NODES + i];
  }
#pragma unroll
  for (int off = 32; off >= 1; off >>= 1) v += __shfl_down(v, off);
  __shared__ int ws[4];
  if ((threadIdx.x & 63) == 0) ws[threadIdx.x >> 6] = v;
  __syncthreads();
  if (threadIdx.x == 0)
    blocksum[blockIdx.x] = ws[0] + ws[1] + ws[2] + ws[3];
}

__global__ __launch_bounds__(256) void scanblk_kernel(
    int* __restrict__ blocksum) {
  __shared__ int s[256];
  const int t = threadIdx.x;
  s[t] = (t < SCAN_BLOCKS) ? blocksum[t] : 0;
  __syncthreads();
#pragma unroll
  for (int off = 1; off < 256; off <<= 1) {
    int v = (t >= off) ? s[t - off] : 0;
    __syncthreads();
    s[t] += v;
    __syncthreads();
  }
  if (t < SCAN_BLOCKS) blocksum[t] = (t == 0) ? 0 : s[t - 1];  // exclusive
}

__global__ __launch_bounds__(256) void final_kernel(
    const int* __restrict__ deg_r, const int* __restrict__ blocksum,
    int* __restrict__ rowptr, int* __restrict__ coff) {
  __shared__ int s[256];
  const int t = threadIdx.x;
  const int i = blockIdx.x * 256 + t;
  int d[NREP];
  int tot = 0;
  if (i < N_NODES) {
#pragma unroll
    for (int r = 0; r < NREP; r++) {
      d[r] = deg_r[r * N_NODES + i];
      tot += d[r];
    }
  }
  s[t] = tot;
  __syncthreads();
#pragma unroll
  for (int off = 1; off < 256; off <<= 1) {
    int v = (t >= off) ? s[t - off] : 0;
    __syncthreads();
    s[t] += v;
    __syncthreads();
  }
  if (i < N_NODES) {
    int pre = blocksum[blockIdx.x] + s[t] - tot;  // exclusive prefix
    rowptr[i] = pre;
    int run = pre;
#pragma unroll
    for (int r = 0; r < NREP; r++) {
      coff[r * N_NODES + i] = run;
      run += d[r];
    }
    if (i == N_NODES - 1) rowptr[N_NODES] = N_EDGES;
  }
}

// ---------------------------------------------------------------------------
// GEMM1 body (device fn): support = bf16(x) @ bf16(W1), fp32 acc, MFMA.
// Row-major support (r7-verified). Called from the fused scatter+gemm kernel.
// ---------------------------------------------------------------------------
__device__ __forceinline__ void gemm1_body(
    int bid, const float* __restrict__ x,
    const unsigned short* __restrict__ W1T,
    unsigned short* __restrict__ support) {
  __shared__ short8 As[512];  // chunk = q*128 + row
  __shared__ short8 Bs[512];  // chunk = q*128 + col
  const int t = threadIdx.x;
  const int lane = t & 63;
  const int w = t >> 6;
  const int quad = lane >> 4;
  const int l15 = lane & 15;
  const int node_base = bid * 128;
  const int mbase = (w >> 1) * 64;
  const int nbase = (w & 1) * 64;

  f32x4 acc[4][4] = {};

  for (int k0 = 0; k0 < NFEAT; k0 += 32) {
#pragma unroll
    for (int i = 0; i < 2; i++) {
      int lin = i * 256 + t;        // 0..511
      int n = lin >> 2, q = lin & 3;
      int row = node_base + n;
      if (row >= N_NODES) row = N_NODES - 1;
      const float* src = &x[(size_t)row * NFEAT + k0 + q * 8];
      float4 a = *(const float4*)src;
      float4 b = *(const float4*)(src + 4);
      short8 p;
      p[0] = (short)f2bu(a.x); p[1] = (short)f2bu(a.y);
      p[2] = (short)f2bu(a.z); p[3] = (short)f2bu(a.w);
      p[4] = (short)f2bu(b.x); p[5] = (short)f2bu(b.y);
      p[6] = (short)f2bu(b.z); p[7] = (short)f2bu(b.w);
      As[q * 128 + n] = p;
      Bs[q * 128 + n] = *(const short8*)&W1T[(size_t)n * NFEAT + k0 + q * 8];
    }
    __syncthreads();
    short8 af[4], bfr[4];
#pragma unroll
    for (int mt = 0; mt < 4; mt++)
      af[mt] = As[quad * 128 + mbase + mt * 16 + l15];
#pragma unroll
    for (int nt = 0; nt < 4; nt++)
      bfr[nt] = Bs[quad * 128 + nbase + nt * 16 + l15];
#pragma unroll
    for (int mt = 0; mt < 4; mt++)
#pragma unroll
      for (int nt = 0; nt < 4; nt++)
        acc[mt][nt] = __builtin_amdgcn_mfma_f32_16x16x32_bf16(
            af[mt], bfr[nt], acc[mt][nt], 0, 0, 0);
    __syncthreads();
  }

#pragma unroll
  for (int mt = 0; mt < 4; mt++)
#pragma unroll
    for (int nt = 0; nt < 4; nt++)
#pragma unroll
      for (int r = 0; r < 4; r++) {
        int row = node_base + mbase + mt * 16 + quad * 4 + r;
        int col = nbase + nt * 16 + l15;
        if (row < N_NODES)
          support[(size_t)row * HIDDEN + col] = f2bu(acc[mt][nt][r]);
      }
}

// ---------------------------------------------------------------------------
// Fused: scatter pass 1 (rows [0,25000), blocks 0..6249) | GEMM1 (blocks
// 6250..6640). Independent; gemm1's ~20us hides under atomic-bound scatter.
// ---------------------------------------------------------------------------
__global__ __launch_bounds__(256) void scatter_gemm1_kernel(
    const int* __restrict__ erow, const unsigned* __restrict__ pval,
    int* __restrict__ coff, unsigned* __restrict__ csr,
    const float* __restrict__ x, const unsigned short* __restrict__ W1T,
    unsigned short* __restrict__ support) {
  if (blockIdx.x < HIST_BLOCKS) {
    unsigned e = blockIdx.x * 256 + threadIdx.x;
    int r = erow[e];
    if (r >= 25000) return;
    int p = atomicAdd(&coff[(blockIdx.x & (NREP - 1)) * N_NODES + r], 1);
    csr[p] = pval[e];
  } else {
    gemm1_body(blockIdx.x - HIST_BLOCKS, x, W1T, support);
  }
}

// scatter pass 2: rows [25000, 50000)
__global__ __launch_bounds__(256) void scatter_kernel(
    const int* __restrict__ erow, const unsigned* __restrict__ pval,
    int* __restrict__ coff, unsigned* __restrict__ csr) {
  unsigned e = blockIdx.x * 256 + threadIdx.x;
  int r = erow[e];
  if (r < 25000) return;
  int p = atomicAdd(&coff[(blockIdx.x & (NREP - 1)) * N_NODES + r], 1);
  csr[p] = pval[e];
}

// ---------------------------------------------------------------------------
// SpMM1 fused (r7 structure, 8 edges in flight): wave per row, lane owns
// cols (2l,2l+1), wave-uniform edge index -> scalar csr loads + scalar
// gather bases. h[row] = bf16(dropout(relu(sum val*support[col] + b1)))
// ---------------------------------------------------------------------------
__global__ __launch_bounds__(256) void spmm1_fused(
    const unsigned* __restrict__ csr, const int* __restrict__ rowptr,
    const unsigned* __restrict__ sup,  // support rows = 64 uints (bf162)
    const float* __restrict__ b1, unsigned* __restrict__ h) {
  const int row = blockIdx.x * 4 + (threadIdx.x >> 6);
  const int lane = threadIdx.x & 63;
  const int beg = rowptr[row], end = rowptr[row + 1];
  float ax = 0.f, ay = 0.f;
  int j = beg;
  for (; j + 7 < end; j += 8) {
    unsigned p0 = csr[j],     p1 = csr[j + 1], p2 = csr[j + 2], p3 = csr[j + 3];
    unsigned p4 = csr[j + 4], p5 = csr[j + 5], p6 = csr[j + 6], p7 = csr[j + 7];
    unsigned u0 = sup[(p0 & 0xffffu) * 64 + lane];
    unsigned u1 = sup[(p1 & 0xffffu) * 64 + lane];
    unsigned u2 = sup[(p2 & 0xffffu) * 64 + lane];
    unsigned u3 = sup[(p3 & 0xffffu) * 64 + lane];
    unsigned u4 = sup[(p4 & 0xffffu) * 64 + lane];
    unsigned u5 = sup[(p5 & 0xffffu) * 64 + lane];
    unsigned u6 = sup[(p6 & 0xffffu) * 64 + lane];
    unsigned u7 = sup[(p7 & 0xffffu) * 64 + lane];
    float v0 = __uint_as_float(p0 & 0xffff0000u);
    float v1 = __uint_as_float(p1 & 0xffff0000u);
    float v2 = __uint_as_float(p2 & 0xffff0000u);
    float v3 = __uint_as_float(p3 & 0xffff0000u);
    float v4 = __uint_as_float(p4 & 0xffff0000u);
    float v5 = __uint_as_float(p5 & 0xffff0000u);
    float v6 = __uint_as_float(p6 & 0xffff0000u);
    float v7 = __uint_as_float(p7 & 0xffff0000u);
    ax += v0 * __uint_as_float(u0 << 16) + v1 * __uint_as_float(u1 << 16) +
          v2 * __uint_as_float(u2 << 16) + v3 * __uint_as_float(u3 << 16) +
          v4 * __uint_as_float(u4 << 16) + v5 * __uint_as_float(u5 << 16) +
          v6 * __uint_as_float(u6 << 16) + v7 * __uint_as_float(u7 << 16);
    ay += v0 * __uint_as_float(u0 & 0xffff0000u) +
          v1 * __uint_as_float(u1 & 0xffff0000u) +
          v2 * __uint_as_float(u2 & 0xffff0000u) +
          v3 * __uint_as_float(u3 & 0xffff0000u) +
          v4 * __uint_as_float(u4 & 0xffff0000u) +
          v5 * __uint_as_float(u5 & 0xffff0000u) +
          v6 * __uint_as_float(u6 & 0xffff0000u) +
          v7 * __uint_as_float(u7 & 0xffff0000u);
  }
  for (; j + 1 < end; j += 2) {
    unsigned p0 = csr[j], p1 = csr[j + 1];
    unsigned u0 = sup[(p0 & 0xffffu) * 64 + lane];
    unsigned u1 = sup[(p1 & 0xffffu) * 64 + lane];
    float v0 = __uint_as_float(p0 & 0xffff0000u);
    float v1 = __uint_as_float(p1 & 0xffff0000u);
    ax += v0 * __uint_as_float(u0 << 16) + v1 * __uint_as_float(u1 << 16);
    ay += v0 * __uint_as_float(u0 & 0xffff0000u) +
          v1 * __uint_as_float(u1 & 0xffff0000u);
  }
  if (j < end) {
    unsigned p0 = csr[j];
    unsigned u0 = sup[(p0 & 0xffffu) * 64 + lane];
    float v0 = __uint_as_float(p0 & 0xffff0000u);
    ax += v0 * __uint_as_float(u0 << 16);
    ay += v0 * __uint_as_float(u0 & 0xffff0000u);
  }
  const unsigned i0 = (unsigned)row * HIDDEN + lane * 2;
  float vx = fmaxf(ax + b1[lane * 2], 0.f);
  float vy = fmaxf(ay + b1[lane * 2 + 1], 0.f);
  vx = (threefry_bits(i0) >> 31) ? 0.f : 2.f * vx;
  vy = (threefry_bits(i0 + 1) >> 31) ? 0.f : 2.f * vy;
  h[(unsigned)row * 64 + lane] = (unsigned)f2bu(vx) | ((unsigned)f2bu(vy) << 16);
}

// ---------------------------------------------------------------------------
// GEMM2: h2[50000,40] = h(bf16) @ W2, fp32 compute, bf16 out. (r4-verified)
// ---------------------------------------------------------------------------
__global__ __launch_bounds__(256) void gemm2_kernel(
    const uint4* __restrict__ h,  // rows = 16 uint4 (8 bf16 each)
    const float* __restrict__ W2, unsigned short* __restrict__ h2) {
  __shared__ float Hs[64][132];
  __shared__ float Ws[40][132];
  const int t = threadIdx.x;
  const int node_base = blockIdx.x * 64;
#pragma unroll
  for (int i = 0; i < 4; i++) {
    int lin = i * 256 + t;
    int nloc = lin >> 4, c8 = lin & 15;
    int n = node_base + nloc;
    if (n >= N_NODES) n = N_NODES - 1;
    uint4 u = h[(size_t)n * 16 + c8];
    float* d = &Hs[nloc][c8 * 8];
    d[0] = __uint_as_float(u.x << 16); d[1] = __uint_as_float(u.x & 0xffff0000u);
    d[2] = __uint_as_float(u.y << 16); d[3] = __uint_as_float(u.y & 0xffff0000u);
    d[4] = __uint_as_float(u.z << 16); d[5] = __uint_as_float(u.z & 0xffff0000u);
    d[6] = __uint_as_float(u.w << 16); d[7] = __uint_as_float(u.w & 0xffff0000u);
  }
#pragma unroll
  for (int i = 0; i < 20; i++) {
    int l = t + i * 256;
    int k = l / NCLASS, f = l % NCLASS;
    Ws[f][k] = W2[l];
  }
  __syncthreads();
  const int nloc = t >> 2;
  const int fb = t & 3;
  const int n = node_base + nloc;
  float acc[10];
#pragma unroll
  for (int j = 0; j < 10; j++) acc[j] = 0.f;
  for (int k = 0; k < HIDDEN; k += 4) {
    float4 a = *(const float4*)&Hs[nloc][k];
#pragma unroll
    for (int j = 0; j < 10; j++) {
      float4 wv = *(const float4*)&Ws[fb + 4 * j][k];
      acc[j] += a.x * wv.x + a.y * wv.y + a.z * wv.z + a.w * wv.w;
    }
  }
  if (n < N_NODES) {
#pragma unroll
    for (int j = 0; j < 10; j++)
      h2[(size_t)n * NCLASS + fb + 4 * j] = f2bu(acc[j]);
  }
}

// ---------------------------------------------------------------------------
// SpMM2 fused: wave per row, 4 edges in flight (half-split x 2-unroll). (r7)
// ---------------------------------------------------------------------------
__global__ __launch_bounds__(256) void spmm2_fused(
    const unsigned* __restrict__ csr, const int* __restrict__ rowptr,
    const unsigned* __restrict__ h2u,  // rows = 20 uints
    const float* __restrict__ b2, float* __restrict__ out) {
  const int row = blockIdx.x * 4 + (threadIdx.x >> 6);
  const int lane = threadIdx.x & 63;
  const int half = lane >> 5;
  const int il = lane & 31;
  const unsigned ilc = (il < 20) ? (unsigned)il : 19u;
  const int beg = rowptr[row], end = rowptr[row + 1];
  float ax = 0.f, ay = 0.f;
  int j = beg + half;
  for (; j + 2 < end; j += 4) {
    unsigned p0 = csr[j];
    unsigned p1 = csr[j + 2];
    unsigned u0 = h2u[(p0 & 0xffffu) * 20 + ilc];
    unsigned u1 = h2u[(p1 & 0xffffu) * 20 + ilc];
    float v0 = __uint_as_float(p0 & 0xffff0000u);
    float v1 = __uint_as_float(p1 & 0xffff0000u);
    ax += v0 * __uint_as_float(u0 << 16) + v1 * __uint_as_float(u1 << 16);
    ay += v0 * __uint_as_float(u0 & 0xffff0000u) +
          v1 * __uint_as_float(u1 & 0xffff0000u);
  }
  for (; j < end; j += 2) {
    unsigned p0 = csr[j];
    unsigned u0 = h2u[(p0 & 0xffffu) * 20 + ilc];
    float v0 = __uint_as_float(p0 & 0xffff0000u);
    ax += v0 * __uint_as_float(u0 << 16);
    ay += v0 * __uint_as_float(u0 & 0xffff0000u);
  }
  ax += __shfl_xor(ax, 32);
  ay += __shfl_xor(ay, 32);
  if (half == 0 && il < 20) {
    float2 r;
    r.x = fmaxf(ax + b2[il * 2], 0.f);
    r.y = fmaxf(ay + b2[il * 2 + 1], 0.f);
    *(float2*)&out[(unsigned)row * NCLASS + il * 2] = r;
  }
}

extern "C" void kernel_launch(void* const* d_in, const int* in_sizes, int n_in,
                              void* d_out, int out_size, void* d_ws,
                              size_t ws_size, hipStream_t stream) {
  const float* x     = (const float*)d_in[0];
  const int*   erow  = (const int*)d_in[1];
  const int*   ecol  = (const int*)d_in[2];
  const float* evals = (const float*)d_in[3];
  const float* W1    = (const float*)d_in[4];
  const float* b1    = (const float*)d_in[5];
  const float* W2    = (const float*)d_in[6];
  const float* b2    = (const float*)d_in[7];
  float* out = (float*)d_out;

  // ws layout (bytes): support 12.8M | h 12.8M | h2 4M | W1T 128K |
  // csr 6.4M | pval 6.4M | rowptr 200K | blocksum 1K | deg_r 1.6M |
  // coff 1.6M   (~46 MB)
  char* base = (char*)d_ws;
  unsigned short* support = (unsigned short*)base;
  unsigned short* h   = (unsigned short*)(base + 12800000);
  unsigned short* h2  = (unsigned short*)(base + 25600000);
  unsigned short* W1T = (unsigned short*)(base + 29600000);
  unsigned* csr  = (unsigned*)(base + 29731072);
  unsigned* pval = (unsigned*)(base + 29731072 + (size_t)N_EDGES * 4);
  int* rowptr   = (int*)(base + 29731072 + (size_t)N_EDGES * 8);
  int* blocksum = rowptr + (N_NODES + 1);
  int* deg_r    = blocksum + 256;
  int* coff     = deg_r + NREP * N_NODES;

  hipMemsetAsync(deg_r, 0, NREP * N_NODES * sizeof(int), stream);

  hist_w1t_kernel<<<HIST_BLOCKS + W1T_BLOCKS, 256, 0, stream>>>(
      erow, ecol, evals, deg_r, pval, W1, W1T);
  partial_kernel<<<SCAN_BLOCKS, 256, 0, stream>>>(deg_r, blocksum);
  scanblk_kernel<<<1, 256, 0, stream>>>(blocksum);
  final_kernel<<<SCAN_BLOCKS, 256, 0, stream>>>(deg_r, blocksum, rowptr, coff);
  // scatter pass 1 (rows [0,25000)) fused with gemm1 (independent work)
  scatter_gemm1_kernel<<<HIST_BLOCKS + GEMM1_BLOCKS, 256, 0, stream>>>(
      erow, pval, coff, csr, x, W1T, support);
  // scatter pass 2 (rows [25000,50000))
  scatter_kernel<<<HIST_BLOCKS, 256, 0, stream>>>(erow, pval, coff, csr);

  spmm1_fused<<<N_NODES / 4, 256, 0, stream>>>(csr, rowptr,
                                               (const unsigned*)support, b1,
                                               (unsigned*)h);
  gemm2_kernel<<<(N_NODES + 63) / 64, 256, 0, stream>>>((const uint4*)h, W2, h2);
  spmm2_fused<<<N_NODES / 4, 256, 0, stream>>>(csr, rowptr,
                                               (const unsigned*)h2, b2, out);
}